// Round 2
// baseline (465.283 us; speedup 1.0000x reference)
//
#include <hip/hip_runtime.h>

// Problem constants
#define S_DIM 8192
#define K_DIM 1024
#define RO_DIM 4096
#define O_DIM 64
#define SO (S_DIM * O_DIM)

typedef __attribute__((ext_vector_type(8))) __bf16 bf16x8;
typedef __attribute__((ext_vector_type(4))) float floatx4;
typedef __attribute__((ext_vector_type(4))) unsigned short ushx4;
typedef __attribute__((ext_vector_type(8))) unsigned short ushx8;

__device__ inline unsigned short f2bf(float f) {
  unsigned u = __builtin_bit_cast(unsigned, f);
  u += 0x7fff + ((u >> 16) & 1);  // round-to-nearest-even
  return (unsigned short)(u >> 16);
}
__device__ inline float bf2f(unsigned short h) {
  unsigned u = ((unsigned)h) << 16;
  return __builtin_bit_cast(float, u);
}

// ---------------------------------------------------------------- cast X,W -> bf16 (+ zero Y)
__global__ __launch_bounds__(256) void cast_kernel(const float* __restrict__ X,
                                                   const float* __restrict__ W,
                                                   unsigned short* __restrict__ Xb,
                                                   unsigned short* __restrict__ Wb,
                                                   float* __restrict__ Y) {
  const int NX4 = (S_DIM * K_DIM) / 4;
  // zero Y (8192x64 fp32 = 131072 float4 groups; blocks 0..511 cover it) so the
  // gemm epilogue can split-K atomicAdd directly into Y (reduce kernel removed).
  int zi = blockIdx.x * 256 + threadIdx.x;
  if (zi < SO / 4) ((float4*)Y)[zi] = (float4){0.f, 0.f, 0.f, 0.f};
#pragma unroll
  for (int i = 0; i < 4; ++i) {
    int g = blockIdx.x * 1024 + i * 256 + threadIdx.x;
    float4 v;
    unsigned short* dst;
    if (g < NX4) {
      v = ((const float4*)X)[g];
      dst = Xb + (size_t)g * 4;
    } else {
      int j = g - NX4;
      v = ((const float4*)W)[j];
      dst = Wb + (size_t)j * 4;
    }
    ushx4 o;
    o.x = f2bf(v.x); o.y = f2bf(v.y); o.z = f2bf(v.z); o.w = f2bf(v.w);
    *(ushx4*)dst = o;
  }
}

// ---------------------------------------------------------------- 256x256 8-phase GEMM
// Quadrant phase split (m201's actual decomposition): per tile kt the 4 phases
// compute output quadrants (mhalf,nhalf); reads per phase: q0 = A mi0-3 + B ni0-1
// (12), q1 = B ni2-3 (4), q2 = A mi4-7 (8), q3 = NONE (pure-MFMA phase -> hosts
// the counted vmcnt with zero lgkm dependency). Stage schedule unchanged from R1:
// q0/q1 -> A(kt+1) halves, q2/q3 -> B(kt+2) halves; vmcnt(4) only at q3.
// XCD remap: XCD x owns bx in {2x,2x+1} (B footprint 1MB/XCD -> L2-resident) and
// the bx-pair sharing an A panel launches 8 ids apart -> co-resident on the same
// XCD -> A's 2nd read is an L2 hit. Staging now served by own-XCD L2, not L3.
// Epilogue: in-block 4-rule LDS reduce, then fp32 unsafeAtomicAdd into Y.

template <int MB, int NB>
__device__ __forceinline__ void mfmaq(floatx4 (&acc)[8][4], const bf16x8 (&afr)[4][2],
                                      const bf16x8 (&bfr)[4][2]) {
  __builtin_amdgcn_s_setprio(1);
#pragma unroll
  for (int m = 0; m < 4; ++m)
#pragma unroll
    for (int n = 0; n < 2; ++n) {
      acc[MB + m][NB + n] = __builtin_amdgcn_mfma_f32_16x16x32_bf16(
          afr[m][0], bfr[NB + n][0], acc[MB + m][NB + n], 0, 0, 0);
      acc[MB + m][NB + n] = __builtin_amdgcn_mfma_f32_16x16x32_bf16(
          afr[m][1], bfr[NB + n][1], acc[MB + m][NB + n], 0, 0, 0);
    }
  __builtin_amdgcn_s_setprio(0);
}

#define BAR() __builtin_amdgcn_s_barrier()
#define LGKM0() asm volatile("s_waitcnt lgkmcnt(0)" ::: "memory")
#define SB0() __builtin_amdgcn_sched_barrier(0)

__global__ __launch_bounds__(512, 2) void gemm_kernel(const unsigned short* __restrict__ Xb,
                                                      const unsigned short* __restrict__ Wb,
                                                      const float* __restrict__ bias,
                                                      const float* __restrict__ lam,
                                                      float* __restrict__ Y) {
  __shared__ __align__(16) unsigned char smem[135168];  // 128KB buffers + 4KB lamsh
  unsigned short* sm = (unsigned short*)smem;
  float* lamsh = (float*)(smem + 131072);  // [256][4]

  const int t = threadIdx.x;
  const int lane = t & 63;
  const int w = t >> 6;
  const int wm = w >> 2;   // M half: rows wm*128..+127
  const int wn = w & 3;    // N quarter = rule index within block
  const int quad = lane >> 4;
  const int l16 = lane & 15;

  // XCD-locality remap: hw XCD = id%8. XCD x gets bx in {2x,2x+1}; pair sharing
  // an A panel (j=2m,2m+1) is 8 dispatch-ids apart -> co-resident on XCD x.
  int id = blockIdx.y * 16 + blockIdx.x;
  int x = id & 7;
  int j = id >> 3;               // 0..63
  const int bx = 2 * x + (j & 1);
  const int by = j >> 1;         // 0..31
  const int gm0 = by * 256;
  const int gn0 = bx * 256;

  // staging per-thread constants (gcc = chunk ^ (row&7) is thread-invariant)
  const int rowt = t >> 3;                       // 0..63
  const int gcc = (t & 7) ^ (rowt & 7);
  const size_t goff = (size_t)rowt * K_DIM + (size_t)gcc * 8;
  const unsigned short* Abase = Xb + (size_t)gm0 * K_DIM;
  const unsigned short* Bbase = Wb + (size_t)gn0 * K_DIM;

  auto STAGE = [&](const unsigned short* gbase, int half, int ktile, int slotOff) {
#pragma unroll
    for (int jj = 0; jj < 2; ++jj) {
      const unsigned short* src =
          gbase + (size_t)(half * 128 + jj * 64) * K_DIM + ktile * 64 + goff;
      __builtin_amdgcn_global_load_lds(
          (const __attribute__((address_space(1))) void*)src,
          (__attribute__((address_space(3))) void*)(sm + slotOff + jj * 4096 + t * 8),
          16, 0, 0);
    }
  };

  // prologue: tile0 (A0,A1,B0,B1 -> buf0) + tile1 B halves (-> buf1): 12 loads.
  STAGE(Abase, 0, 0, 0);
  STAGE(Abase, 1, 0, 8192);
  STAGE(Bbase, 0, 0, 16384);
  STAGE(Bbase, 1, 0, 24576);
  STAGE(Bbase, 0, 1, 32768 + 16384);
  STAGE(Bbase, 1, 1, 32768 + 24576);

  {
    int i = t;
    lamsh[i] = lam[(size_t)(gm0 + (i >> 2)) * 64 + bx * 4 + (i & 3)];
    i = t + 512;
    lamsh[i] = lam[(size_t)(gm0 + (i >> 2)) * 64 + bx * 4 + (i & 3)];
  }
  asm volatile("s_waitcnt vmcnt(4)" ::: "memory");
  BAR();

  // acc init = bias (exact fold). Bias/lam loads are older than tile0's stages,
  // so tile0 q3's vmcnt(4) drains them along with A(1) — accounting stays exact.
  floatx4 acc[8][4];
#pragma unroll
  for (int ni = 0; ni < 4; ++ni) {
    float bv = bias[gn0 + wn * 64 + ni * 16 + l16];
#pragma unroll
    for (int mi = 0; mi < 8; ++mi) acc[mi][ni] = (floatx4){bv, bv, bv, bv};
  }

  const int cA0 = ((quad) ^ (l16 & 7)) * 8;        // k-chunk ks=0, swizzled
  const int cA1 = ((4 + quad) ^ (l16 & 7)) * 8;    // k-chunk ks=1, swizzled

  for (int kt = 0; kt < 16; ++kt) {
    const int b = kt & 1;
    const unsigned short* As = sm + b * 32768 + wm * 8192 + l16 * 64;
    const unsigned short* Bs = sm + b * 32768 + 16384 + wn * 4096 + l16 * 64;
    const int bufA = (b ^ 1) * 32768;  // A stages -> tile kt+1's buffer
    const int bufB = b * 32768;        // B stages -> tile kt+2's buffer (==b)

    bf16x8 afr[4][2], bfr[4][2];

    // ---- q0: read A mi0-3 + B ni0-1; stage A(kt+1) h0
#pragma unroll
    for (int m = 0; m < 4; ++m) {
      afr[m][0] = *(const bf16x8*)(As + m * 1024 + cA0);
      afr[m][1] = *(const bf16x8*)(As + m * 1024 + cA1);
    }
#pragma unroll
    for (int n = 0; n < 2; ++n) {
      bfr[n][0] = *(const bf16x8*)(Bs + n * 1024 + cA0);
      bfr[n][1] = *(const bf16x8*)(Bs + n * 1024 + cA1);
    }
    if (kt < 15) STAGE(Abase, 0, kt + 1, bufA);
    BAR();
    LGKM0();
    SB0();
    mfmaq<0, 0>(acc, afr, bfr);
    BAR();

    // ---- q1: read B ni2-3; stage A(kt+1) h1
#pragma unroll
    for (int n = 2; n < 4; ++n) {
      bfr[n][0] = *(const bf16x8*)(Bs + n * 1024 + cA0);
      bfr[n][1] = *(const bf16x8*)(Bs + n * 1024 + cA1);
    }
    if (kt < 15) STAGE(Abase, 1, kt + 1, bufA + 8192);
    BAR();
    LGKM0();
    SB0();
    mfmaq<0, 2>(acc, afr, bfr);
    BAR();

    // ---- q2: read A mi4-7; stage B(kt+2) h0
#pragma unroll
    for (int m = 0; m < 4; ++m) {
      afr[m][0] = *(const bf16x8*)(As + (4 + m) * 1024 + cA0);
      afr[m][1] = *(const bf16x8*)(As + (4 + m) * 1024 + cA1);
    }
    if (kt < 14) STAGE(Bbase, 0, kt + 2, bufB + 16384);
    BAR();
    LGKM0();
    SB0();
    mfmaq<4, 0>(acc, afr, bfr);
    BAR();

    // ---- q3: NO reads (operands all in regs); stage B(kt+2) h1; counted vmcnt
    if (kt < 14) {
      STAGE(Bbase, 1, kt + 2, bufB + 24576);
      asm volatile("s_waitcnt vmcnt(4)" ::: "memory");
    } else if (kt == 14) {
      asm volatile("s_waitcnt vmcnt(0)" ::: "memory");  // tail: A(15) must land
    }
    BAR();
    SB0();
    mfmaq<4, 2>(acc, afr, bfr);
    BAR();
  }

  // ---- epilogue: rule-weighted sigmoid -> LDS (bf16), 4-rule in-block reduce,
  // then fp32 split-K atomicAdd into Y (no reduce kernel, one fewer rounding).
  __syncthreads();
  {
    unsigned short* yreg = sm + wn * 16384;  // [256][64], col-chunk ^= quad (banks)
#pragma unroll
    for (int mi = 0; mi < 8; ++mi) {
#pragma unroll
      for (int r = 0; r < 4; ++r) {
        int row = wm * 128 + mi * 16 + quad * 4 + r;
        float lamv = lamsh[row * 4 + wn];
#pragma unroll
        for (int ni = 0; ni < 4; ++ni) {
          float sg = 1.f / (1.f + __expf(-acc[mi][ni][r]));
          yreg[row * 64 + ((ni ^ quad) * 16) + l16] = f2bf(lamv * sg);
        }
      }
    }
  }
  __syncthreads();
  {
    float* Yb = Y + (size_t)gm0 * 64;
#pragma unroll
    for (int g = 0; g < 4; ++g) {
      int idx = g * 4096 + t * 8;  // lane-contiguous
      int row = idx >> 6;
      int c = idx & 63;
      int phys = row * 64 + ((((c >> 4) ^ ((row >> 2) & 3))) << 4) + (c & 15);
      float s[8];
#pragma unroll
      for (int jj = 0; jj < 8; ++jj) s[jj] = 0.f;
#pragma unroll
      for (int q = 0; q < 4; ++q) {
        ushx8 v = *(const ushx8*)(sm + q * 16384 + phys);
#pragma unroll
        for (int jj = 0; jj < 8; ++jj) s[jj] += bf2f(v[jj]);
      }
#pragma unroll
      for (int jj = 0; jj < 8; ++jj) unsafeAtomicAdd(Yb + idx + jj, s[jj]);
    }
  }
}

extern "C" void kernel_launch(void* const* d_in, const int* in_sizes, int n_in,
                              void* d_out, int out_size, void* d_ws, size_t ws_size,
                              hipStream_t stream) {
  const float* X = (const float*)d_in[0];     // [8192,1024]
  const float* W = (const float*)d_in[1];     // [4096,1024]
  const float* b = (const float*)d_in[2];     // [4096]
  const float* lam = (const float*)d_in[3];   // [8192,64]
  float* Y = (float*)d_out;                   // [8192,64]

  unsigned short* Xb = (unsigned short*)d_ws;                 // 16 MB
  unsigned short* Wb = Xb + (size_t)S_DIM * K_DIM;            // 8 MB

  int nCast = ((S_DIM + RO_DIM) * K_DIM / 4) / 1024;  // 3072 blocks
  cast_kernel<<<nCast, 256, 0, stream>>>(X, W, Xb, Wb, Y);

  dim3 g(RO_DIM / 256, S_DIM / 256);  // (16, 32) = 512 blocks, 512 threads
  gemm_kernel<<<g, 512, 0, stream>>>(Xb, Wb, b, lam, Y);
}

// Round 3
// 167.315 us; speedup vs baseline: 2.7809x; 2.7809x over previous
//
#include <hip/hip_runtime.h>

// Problem constants
#define S_DIM 8192
#define K_DIM 1024
#define RO_DIM 4096
#define O_DIM 64
#define SO (S_DIM * O_DIM)
#define NSLICE 16  // N/256 partial slices

typedef __attribute__((ext_vector_type(8))) __bf16 bf16x8;
typedef __attribute__((ext_vector_type(4))) float floatx4;
typedef __attribute__((ext_vector_type(4))) unsigned short ushx4;
typedef __attribute__((ext_vector_type(8))) unsigned short ushx8;

__device__ inline unsigned short f2bf(float f) {
  unsigned u = __builtin_bit_cast(unsigned, f);
  u += 0x7fff + ((u >> 16) & 1);  // round-to-nearest-even
  return (unsigned short)(u >> 16);
}
__device__ inline float bf2f(unsigned short h) {
  unsigned u = ((unsigned)h) << 16;
  return __builtin_bit_cast(float, u);
}

// ---------------------------------------------------------------- cast X,W -> bf16
__global__ __launch_bounds__(256) void cast_kernel(const float* __restrict__ X,
                                                   const float* __restrict__ W,
                                                   unsigned short* __restrict__ Xb,
                                                   unsigned short* __restrict__ Wb) {
  const int NX4 = (S_DIM * K_DIM) / 4;
#pragma unroll
  for (int i = 0; i < 4; ++i) {
    int g = blockIdx.x * 1024 + i * 256 + threadIdx.x;
    float4 v;
    unsigned short* dst;
    if (g < NX4) {
      v = ((const float4*)X)[g];
      dst = Xb + (size_t)g * 4;
    } else {
      int j = g - NX4;
      v = ((const float4*)W)[j];
      dst = Wb + (size_t)j * 4;
    }
    ushx4 o;
    o.x = f2bf(v.x); o.y = f2bf(v.y); o.z = f2bf(v.z); o.w = f2bf(v.w);
    *(ushx4*)dst = o;
  }
}

// ---------------------------------------------------------------- 256x256 8-phase GEMM
// R3 changes vs R2: (1) epilogue reverted to bf16 partial slices + reduce kernel
// (R2's cross-XCD atomicAdd made every Y line ping-pong: WRITE 16->262MB, -4.8x).
// (2) Deeper prefetch, vmcnt(6): stages per tile kt are q0 -> A(kt+1)h1,
// q2 -> B(kt+2)h0, q3 -> B(kt+2)h1 + A(kt+2)h0 (A h0 one tile earlier than R2;
// legal: current buffer's A region is last read at q2, B halves at q1 -> targets
// free). Wait moves AFTER q3's MFMA. Per-wave in-order proof: at q3 the 8
// outstanding are [A(kt+1)h1, B(kt+2)h0, B(kt+2)h1, A(kt+2)h0]; vmcnt(6)
// retires exactly A(kt+1)h1 = the only data next q0 still needs. Slack for A
// grows from ~3 phases (< L3 latency ~600-900cy -> per-tile stall) to 4.5-7.5.
// Tail: kt=14 -> vmcnt(0); kt=15 no stages. (3) q3 keeps zero ds_reads.
// XCD remap kept: XCD x owns bx in {2x,2x+1} (B 1MB/XCD -> L2-resident); A-panel
// pair 8 ids apart -> co-resident, 2nd read L2-hit.

template <int MB, int NB>
__device__ __forceinline__ void mfmaq(floatx4 (&acc)[8][4], const bf16x8 (&afr)[4][2],
                                      const bf16x8 (&bfr)[4][2]) {
  __builtin_amdgcn_s_setprio(1);
#pragma unroll
  for (int m = 0; m < 4; ++m)
#pragma unroll
    for (int n = 0; n < 2; ++n) {
      acc[MB + m][NB + n] = __builtin_amdgcn_mfma_f32_16x16x32_bf16(
          afr[m][0], bfr[NB + n][0], acc[MB + m][NB + n], 0, 0, 0);
      acc[MB + m][NB + n] = __builtin_amdgcn_mfma_f32_16x16x32_bf16(
          afr[m][1], bfr[NB + n][1], acc[MB + m][NB + n], 0, 0, 0);
    }
  __builtin_amdgcn_s_setprio(0);
}

#define BAR() __builtin_amdgcn_s_barrier()
#define LGKM0() asm volatile("s_waitcnt lgkmcnt(0)" ::: "memory")
#define SB0() __builtin_amdgcn_sched_barrier(0)

__global__ __launch_bounds__(512, 2) void gemm_kernel(const unsigned short* __restrict__ Xb,
                                                      const unsigned short* __restrict__ Wb,
                                                      const float* __restrict__ bias,
                                                      const float* __restrict__ lam,
                                                      unsigned short* __restrict__ partial) {
  __shared__ __align__(16) unsigned char smem[135168];  // 128KB buffers + 4KB lamsh
  unsigned short* sm = (unsigned short*)smem;
  float* lamsh = (float*)(smem + 131072);  // [256][4]

  const int t = threadIdx.x;
  const int lane = t & 63;
  const int w = t >> 6;
  const int wm = w >> 2;   // M half: rows wm*128..+127
  const int wn = w & 3;    // N quarter = rule index within block
  const int quad = lane >> 4;
  const int l16 = lane & 15;

  // XCD-locality remap: hw XCD = id%8. XCD x gets bx in {2x,2x+1}; pair sharing
  // an A panel (j even/odd) is 8 dispatch-ids apart -> co-resident on XCD x.
  int id = blockIdx.y * 16 + blockIdx.x;
  int x = id & 7;
  int j = id >> 3;               // 0..63
  const int bx = 2 * x + (j & 1);
  const int by = j >> 1;         // 0..31
  const int gm0 = by * 256;
  const int gn0 = bx * 256;

  // staging per-thread constants (gcc = chunk ^ (row&7) is thread-invariant)
  const int rowt = t >> 3;                       // 0..63
  const int gcc = (t & 7) ^ (rowt & 7);
  const size_t goff = (size_t)rowt * K_DIM + (size_t)gcc * 8;
  const unsigned short* Abase = Xb + (size_t)gm0 * K_DIM;
  const unsigned short* Bbase = Wb + (size_t)gn0 * K_DIM;

  auto STAGE = [&](const unsigned short* gbase, int half, int ktile, int slotOff) {
#pragma unroll
    for (int jj = 0; jj < 2; ++jj) {
      const unsigned short* src =
          gbase + (size_t)(half * 128 + jj * 64) * K_DIM + ktile * 64 + goff;
      __builtin_amdgcn_global_load_lds(
          (const __attribute__((address_space(1))) void*)src,
          (__attribute__((address_space(3))) void*)(sm + slotOff + jj * 4096 + t * 8),
          16, 0, 0);
    }
  };

  // prologue: tile0 full (buf0), tile1 B halves + A h0 (buf1): 14 loads.
  STAGE(Abase, 0, 0, 0);
  STAGE(Abase, 1, 0, 8192);
  STAGE(Bbase, 0, 0, 16384);
  STAGE(Bbase, 1, 0, 24576);
  STAGE(Bbase, 0, 1, 32768 + 16384);
  STAGE(Bbase, 1, 1, 32768 + 24576);
  STAGE(Abase, 0, 1, 32768 + 0);

  {
    int i = t;
    lamsh[i] = lam[(size_t)(gm0 + (i >> 2)) * 64 + bx * 4 + (i & 3)];
    i = t + 512;
    lamsh[i] = lam[(size_t)(gm0 + (i >> 2)) * 64 + bx * 4 + (i & 3)];
  }
  // retire tile0's 8 loads (+B1h0); leaves <=6: B1h1, A1h0, lam
  asm volatile("s_waitcnt vmcnt(6)" ::: "memory");
  BAR();

  // acc init = bias (exact fold); bias loads sit in the vmcnt window as OLDER
  // ops than all loop stages -> every later counted wait only tightens.
  floatx4 acc[8][4];
#pragma unroll
  for (int ni = 0; ni < 4; ++ni) {
    float bv = bias[gn0 + wn * 64 + ni * 16 + l16];
#pragma unroll
    for (int mi = 0; mi < 8; ++mi) acc[mi][ni] = (floatx4){bv, bv, bv, bv};
  }

  const int cA0 = ((quad) ^ (l16 & 7)) * 8;        // k-chunk ks=0, swizzled
  const int cA1 = ((4 + quad) ^ (l16 & 7)) * 8;    // k-chunk ks=1, swizzled

  for (int kt = 0; kt < 16; ++kt) {
    const int b = kt & 1;
    const unsigned short* As = sm + b * 32768 + wm * 8192 + l16 * 64;
    const unsigned short* Bs = sm + b * 32768 + 16384 + wn * 4096 + l16 * 64;
    const int bufN = (b ^ 1) * 32768;  // tile kt+1's buffer
    const int bufC = b * 32768;        // tile kt+2's buffer (== current)

    bf16x8 afr[4][2], bfr[4][2];

    // ---- q0: read A mi0-3 + B ni0-1; stage A(kt+1) h1
#pragma unroll
    for (int m = 0; m < 4; ++m) {
      afr[m][0] = *(const bf16x8*)(As + m * 1024 + cA0);
      afr[m][1] = *(const bf16x8*)(As + m * 1024 + cA1);
    }
#pragma unroll
    for (int n = 0; n < 2; ++n) {
      bfr[n][0] = *(const bf16x8*)(Bs + n * 1024 + cA0);
      bfr[n][1] = *(const bf16x8*)(Bs + n * 1024 + cA1);
    }
    if (kt < 15) STAGE(Abase, 1, kt + 1, bufN + 8192);
    BAR();
    LGKM0();
    SB0();
    mfmaq<0, 0>(acc, afr, bfr);
    BAR();

    // ---- q1: read B ni2-3 (B halves still being read -> no B stage here)
#pragma unroll
    for (int n = 2; n < 4; ++n) {
      bfr[n][0] = *(const bf16x8*)(Bs + n * 1024 + cA0);
      bfr[n][1] = *(const bf16x8*)(Bs + n * 1024 + cA1);
    }
    BAR();
    LGKM0();
    SB0();
    mfmaq<0, 2>(acc, afr, bfr);
    BAR();

    // ---- q2: read A mi4-7; stage B(kt+2) h0 (B slots free after q1)
#pragma unroll
    for (int m = 0; m < 4; ++m) {
      afr[m][0] = *(const bf16x8*)(As + (4 + m) * 1024 + cA0);
      afr[m][1] = *(const bf16x8*)(As + (4 + m) * 1024 + cA1);
    }
    if (kt < 14) STAGE(Bbase, 0, kt + 2, bufC + 16384);
    BAR();
    LGKM0();
    SB0();
    mfmaq<4, 0>(acc, afr, bfr);
    BAR();

    // ---- q3: zero reads; stage B(kt+2) h1 + A(kt+2) h0 (A slots free after q2);
    // pure-MFMA phase hosts the counted wait AFTER the cluster.
    if (kt < 14) {
      STAGE(Bbase, 1, kt + 2, bufC + 24576);
      STAGE(Abase, 0, kt + 2, bufC + 0);
    }
    SB0();
    mfmaq<4, 2>(acc, afr, bfr);
    SB0();
    if (kt < 14) {
      asm volatile("s_waitcnt vmcnt(6)" ::: "memory");  // retires A(kt+1)h1
    } else if (kt == 14) {
      asm volatile("s_waitcnt vmcnt(0)" ::: "memory");  // tail: A(15) must land
    }
    BAR();
  }

  // ---- epilogue: rule-weighted sigmoid -> LDS (bf16), 4-rule in-block reduce,
  // bf16 partial slice write (contention-free; reduce kernel finishes).
  __syncthreads();
  {
    unsigned short* yreg = sm + wn * 16384;  // [256][64], col-chunk ^= quad (banks)
#pragma unroll
    for (int mi = 0; mi < 8; ++mi) {
#pragma unroll
      for (int r = 0; r < 4; ++r) {
        int row = wm * 128 + mi * 16 + quad * 4 + r;
        float lamv = lamsh[row * 4 + wn];
#pragma unroll
        for (int ni = 0; ni < 4; ++ni) {
          float sg = 1.f / (1.f + __expf(-acc[mi][ni][r]));
          yreg[row * 64 + ((ni ^ quad) * 16) + l16] = f2bf(lamv * sg);
        }
      }
    }
  }
  __syncthreads();
  {
    unsigned short* pb = partial + (size_t)bx * SO + (size_t)gm0 * 64;
#pragma unroll
    for (int g = 0; g < 4; ++g) {
      int idx = g * 4096 + t * 8;  // lane-contiguous
      int row = idx >> 6;
      int c = idx & 63;
      int phys = row * 64 + ((((c >> 4) ^ ((row >> 2) & 3))) << 4) + (c & 15);
      float s[8];
#pragma unroll
      for (int jj = 0; jj < 8; ++jj) s[jj] = 0.f;
#pragma unroll
      for (int q = 0; q < 4; ++q) {
        ushx8 v = *(const ushx8*)(sm + q * 16384 + phys);
#pragma unroll
        for (int jj = 0; jj < 8; ++jj) s[jj] += bf2f(v[jj]);
      }
      ushx8 o;
#pragma unroll
      for (int jj = 0; jj < 8; ++jj) o[jj] = f2bf(s[jj]);
      *(ushx8*)(pb + idx) = o;
    }
  }
}

// ---------------------------------------------------------------- final reduce over 16 N-tiles
__global__ __launch_bounds__(256) void reduce_kernel(const unsigned short* __restrict__ partial,
                                                     float* __restrict__ Y) {
  int i4 = blockIdx.x * 256 + threadIdx.x;
  float s0 = 0.f, s1 = 0.f, s2 = 0.f, s3 = 0.f;
#pragma unroll
  for (int c = 0; c < NSLICE; ++c) {
    ushx4 v = ((const ushx4*)(partial + (size_t)c * SO))[i4];
    s0 += bf2f(v.x); s1 += bf2f(v.y); s2 += bf2f(v.z); s3 += bf2f(v.w);
  }
  ((float4*)Y)[i4] = (float4){s0, s1, s2, s3};
}

extern "C" void kernel_launch(void* const* d_in, const int* in_sizes, int n_in,
                              void* d_out, int out_size, void* d_ws, size_t ws_size,
                              hipStream_t stream) {
  const float* X = (const float*)d_in[0];     // [8192,1024]
  const float* W = (const float*)d_in[1];     // [4096,1024]
  const float* b = (const float*)d_in[2];     // [4096]
  const float* lam = (const float*)d_in[3];   // [8192,64]
  float* Y = (float*)d_out;                   // [8192,64]

  unsigned short* Xb = (unsigned short*)d_ws;                 // 16 MB
  unsigned short* Wb = Xb + (size_t)S_DIM * K_DIM;            // 8 MB
  unsigned short* partial = Wb + (size_t)RO_DIM * K_DIM;      // 16 slices x 1 MB

  int nCast = ((S_DIM + RO_DIM) * K_DIM / 4) / 1024;  // 3072 blocks
  cast_kernel<<<nCast, 256, 0, stream>>>(X, W, Xb, Wb);

  dim3 g(RO_DIM / 256, S_DIM / 256);  // (16, 32) = 512 blocks, 512 threads
  gemm_kernel<<<g, 512, 0, stream>>>(Xb, Wb, b, lam, partial);

  reduce_kernel<<<SO / 1024, 256, 0, stream>>>(partial, Y);
}